// Round 3
// baseline (277.730 us; speedup 1.0000x reference)
//
#include <hip/hip_runtime.h>

// ---- constants for B=4, S=2048, D=768, H=12, HD=64 ----
#define BB 4
#define SS 2048
#define DD 768
#define HH 12
#define HDD 64
#define BS (BB*SS)            // 8192 rows
#define NQKV (3*DD)           // 2304
#define NEL (BS*DD)           // 6291456

typedef __attribute__((ext_vector_type(8))) __bf16 bf16x8;
typedef __attribute__((ext_vector_type(4))) float fx4;
typedef __attribute__((ext_vector_type(4))) int   ix4;

#define MFMA16(a,b,c) __builtin_amdgcn_mfma_f32_16x16x32_bf16((a),(b),(c),0,0,0)

// async global->LDS, 16B per lane, lane-linear dest (wave-uniform base + lane*16)
#define GLLDS(g, l) __builtin_amdgcn_global_load_lds( \
    (const __attribute__((address_space(1))) void*)(g), \
    (__attribute__((address_space(3))) void*)(l), 16, 0, 0)

__device__ __forceinline__ unsigned short f2bf(float f) {
  unsigned u = __builtin_bit_cast(unsigned, f);
  u = (u + 0x7FFFu + ((u >> 16) & 1u)) >> 16;
  return (unsigned short)u;
}
// pack two fp32 -> bf16 pair
__device__ __forceinline__ unsigned pkbf(float a, float b) {
  unsigned ua = __builtin_bit_cast(unsigned, a);
  unsigned ub = __builtin_bit_cast(unsigned, b);
  return ((ua + 0x8000u) >> 16) | ((ub + 0x8000u) & 0xFFFF0000u);
}
// hardware packed fp32->bf16 (RNE), 1 instr for 2 elems
__device__ __forceinline__ unsigned cvtpk(float a, float b) {
  unsigned r;
  asm("v_cvt_pk_bf16_f32 %0, %1, %2" : "=v"(r) : "v"(a), "v"(b));
  return r;
}
__device__ __forceinline__ float ex2(float x) { return __builtin_amdgcn_exp2f(x); }

// ---- pack fp32 -> bf16 (vectorized, 4 elems/thread) ----
__global__ __launch_bounds__(256) void pack_bf16(const float* __restrict__ x,
                                                 unsigned short* __restrict__ y, int n4) {
  int i = blockIdx.x * 256 + threadIdx.x;
  if (i < n4) {
    float4 v = ((const float4*)x)[i];
    ((uint2*)y)[i] = make_uint2(pkbf(v.x, v.y), pkbf(v.z, v.w));
  }
}

// ---- mask -> softmax coefficients: p = exp2(sc*ka + kb) ----
//   ka = m * 0.125*log2(e);  kb = (m-1)*1e10*log2(e)
__global__ __launch_bounds__(256) void mask_coef_k(const float* __restrict__ m,
                                                   float* __restrict__ ka,
                                                   float* __restrict__ kb, int n) {
  int i = blockIdx.x * 256 + threadIdx.x;
  if (i < n) {
    float v = m[i];
    ka[i] = v * 0.18033688f;
    kb[i] = __builtin_fmaf(v, 1.44269504e10f, -1.44269504e10f);
  }
}

// ---- tiled pack+transpose: w (K x N) fp32 -> wT (N x K) bf16 ----
__global__ __launch_bounds__(256) void pack_transpose(const float* __restrict__ w,
                                                      unsigned short* __restrict__ wT,
                                                      int K, int N) {
  __shared__ unsigned short t[32][33];
  int n0 = blockIdx.x * 32, k0 = blockIdx.y * 32;
  int tx = threadIdx.x & 31, ty = threadIdx.x >> 5;
#pragma unroll
  for (int r = ty; r < 32; r += 8)
    t[tx][r] = f2bf(w[(size_t)(k0 + r) * N + n0 + tx]);
  __syncthreads();
#pragma unroll
  for (int r = ty; r < 32; r += 8)
    wT[(size_t)(n0 + r) * K + k0 + tx] = t[r][tx];
}

// ==== QKV GEMM: C^T[feature][seq] = Wt(2304x768) x X(8192x768)^T ====
// 128x128 tile, BK=32, double-buffered GLLDS (T3 minimum 2-phase: 1 barrier/tile,
// loads for t+1 in flight under compute of t), 4 waves x 64x64.
__global__ __launch_bounds__(256) void gemm_qkv_k(const unsigned short* __restrict__ Wt,
                                                  const unsigned short* __restrict__ X,
                                                  unsigned short* __restrict__ Qo,
                                                  unsigned short* __restrict__ Ko,
                                                  unsigned short* __restrict__ Vto) {
  __shared__ unsigned short As[2 * 128 * 32];   // 2 x 8KB
  __shared__ unsigned short Bs[2 * 128 * 32];
  const int tid = threadIdx.x;
  const int w = tid >> 6, lane = tid & 63, quad = lane >> 4, l16 = lane & 15;
  const int m0 = blockIdx.y << 7;   // feature
  const int n0 = blockIdx.x << 7;   // seq row
  const int wm = (w & 1) * 64, wn = (w >> 1) * 64;
  fx4 acc[4][4];
#pragma unroll
  for (int i = 0; i < 4; ++i)
#pragma unroll
    for (int c = 0; c < 4; ++c) acc[i][c] = (fx4){0.f, 0.f, 0.f, 0.f};

  const int c0 = tid, c1 = 256 + tid;
  const unsigned short* Ag0 = Wt + (size_t)(m0 + (c0 >> 2)) * DD + (c0 & 3) * 8;
  const unsigned short* Ag1 = Wt + (size_t)(m0 + (c1 >> 2)) * DD + (c1 & 3) * 8;
  const unsigned short* Bg0 = X + (size_t)(n0 + (c0 >> 2)) * DD + (c0 & 3) * 8;
  const unsigned short* Bg1 = X + (size_t)(n0 + (c1 >> 2)) * DD + (c1 & 3) * 8;
  const int wb = w * 1024;   // wave's lane-linear LDS byte base

  // prologue: tile 0 -> buf 0
  GLLDS(Ag0, (char*)As + wb);
  GLLDS(Ag1, (char*)As + 4096 + wb);
  GLLDS(Bg0, (char*)Bs + wb);
  GLLDS(Bg1, (char*)Bs + 4096 + wb);
  int cur = 0;

  for (int k0 = 0; k0 < DD; k0 += 32) {
    __syncthreads();   // drains vmcnt -> buf[cur] ready; prev reads of buf[cur^1] done
    if (k0 + 32 < DD) {
      GLLDS(Ag0 + k0 + 32, (char*)As + (cur ^ 1) * 8192 + wb);
      GLLDS(Ag1 + k0 + 32, (char*)As + (cur ^ 1) * 8192 + 4096 + wb);
      GLLDS(Bg0 + k0 + 32, (char*)Bs + (cur ^ 1) * 8192 + wb);
      GLLDS(Bg1 + k0 + 32, (char*)Bs + (cur ^ 1) * 8192 + 4096 + wb);
    }
    const unsigned short* Asc = As + cur * 4096;
    const unsigned short* Bsc = Bs + cur * 4096;
    bf16x8 af[4], bf[4];
#pragma unroll
    for (int i = 0; i < 4; ++i) af[i] = *(const bf16x8*)&Asc[(wm + i * 16 + l16) * 32 + quad * 8];
#pragma unroll
    for (int c = 0; c < 4; ++c) bf[c] = *(const bf16x8*)&Bsc[(wn + c * 16 + l16) * 32 + quad * 8];
#pragma unroll
    for (int i = 0; i < 4; ++i)
#pragma unroll
      for (int c = 0; c < 4; ++c) acc[i][c] = MFMA16(af[i], bf[c], acc[i][c]);
    cur ^= 1;
  }

  const int which = m0 / DD;  // block-uniform: 0=Q 1=K 2=V (768 = 6*128, no straddle)
#pragma unroll
  for (int i = 0; i < 4; ++i) {
    int fb = m0 + wm + i * 16 + quad * 4;
    int d = fb - which * DD;
    int h = d >> 6, hd = d & 63;
#pragma unroll
    for (int c = 0; c < 4; ++c) {
      int srow = n0 + wn + c * 16 + l16;
      int b = srow >> 11, s = srow & (SS - 1);
      if (which == 0) {
        uint2 v = make_uint2(pkbf(acc[i][c][0], acc[i][c][1]), pkbf(acc[i][c][2], acc[i][c][3]));
        *(uint2*)&Qo[((size_t)(b * HH + h) * SS + s) * HDD + hd] = v;
      } else if (which == 1) {
        uint2 v = make_uint2(pkbf(acc[i][c][0], acc[i][c][1]), pkbf(acc[i][c][2], acc[i][c][3]));
        *(uint2*)&Ko[((size_t)(b * HH + h) * SS + s) * HDD + hd] = v;
      } else {
#pragma unroll
        for (int r = 0; r < 4; ++r)
          Vto[((size_t)(b * HH + h) * HDD + hd + r) * SS + s] = f2bf(acc[i][c][r]);
      }
    }
  }
}

// ==== proj GEMM: C^T[feat][seq] = WprojT(768x768) x Ao(8192x768)^T ====
// epilogue: + b_proj + residual(ctx), fp32 out (feeds LN)
__global__ __launch_bounds__(256) void gemm_proj_k(const unsigned short* __restrict__ Wt,
                                                   const unsigned short* __restrict__ X,
                                                   const float* __restrict__ ctx,
                                                   const float* __restrict__ bproj,
                                                   float* __restrict__ xf) {
  __shared__ unsigned short As[2 * 128 * 32];
  __shared__ unsigned short Bs[2 * 128 * 32];
  const int tid = threadIdx.x;
  const int w = tid >> 6, lane = tid & 63, quad = lane >> 4, l16 = lane & 15;
  const int m0 = blockIdx.y << 7;
  const int n0 = blockIdx.x << 7;
  const int wm = (w & 1) * 64, wn = (w >> 1) * 64;
  fx4 acc[4][4];
#pragma unroll
  for (int i = 0; i < 4; ++i)
#pragma unroll
    for (int c = 0; c < 4; ++c) acc[i][c] = (fx4){0.f, 0.f, 0.f, 0.f};

  const int c0 = tid, c1 = 256 + tid;
  const unsigned short* Ag0 = Wt + (size_t)(m0 + (c0 >> 2)) * DD + (c0 & 3) * 8;
  const unsigned short* Ag1 = Wt + (size_t)(m0 + (c1 >> 2)) * DD + (c1 & 3) * 8;
  const unsigned short* Bg0 = X + (size_t)(n0 + (c0 >> 2)) * DD + (c0 & 3) * 8;
  const unsigned short* Bg1 = X + (size_t)(n0 + (c1 >> 2)) * DD + (c1 & 3) * 8;
  const int wb = w * 1024;

  GLLDS(Ag0, (char*)As + wb);
  GLLDS(Ag1, (char*)As + 4096 + wb);
  GLLDS(Bg0, (char*)Bs + wb);
  GLLDS(Bg1, (char*)Bs + 4096 + wb);
  int cur = 0;

  for (int k0 = 0; k0 < DD; k0 += 32) {
    __syncthreads();
    if (k0 + 32 < DD) {
      GLLDS(Ag0 + k0 + 32, (char*)As + (cur ^ 1) * 8192 + wb);
      GLLDS(Ag1 + k0 + 32, (char*)As + (cur ^ 1) * 8192 + 4096 + wb);
      GLLDS(Bg0 + k0 + 32, (char*)Bs + (cur ^ 1) * 8192 + wb);
      GLLDS(Bg1 + k0 + 32, (char*)Bs + (cur ^ 1) * 8192 + 4096 + wb);
    }
    const unsigned short* Asc = As + cur * 4096;
    const unsigned short* Bsc = Bs + cur * 4096;
    bf16x8 af[4], bf[4];
#pragma unroll
    for (int i = 0; i < 4; ++i) af[i] = *(const bf16x8*)&Asc[(wm + i * 16 + l16) * 32 + quad * 8];
#pragma unroll
    for (int c = 0; c < 4; ++c) bf[c] = *(const bf16x8*)&Bsc[(wn + c * 16 + l16) * 32 + quad * 8];
#pragma unroll
    for (int i = 0; i < 4; ++i)
#pragma unroll
      for (int c = 0; c < 4; ++c) acc[i][c] = MFMA16(af[i], bf[c], acc[i][c]);
    cur ^= 1;
  }

#pragma unroll
  for (int i = 0; i < 4; ++i) {
    int fb = m0 + wm + i * 16 + quad * 4;
    float4 bp = *(const float4*)&bproj[fb];
#pragma unroll
    for (int c = 0; c < 4; ++c) {
      int srow = n0 + wn + c * 16 + l16;
      float4 cx = *(const float4*)&ctx[(size_t)srow * DD + fb];
      float4 r;
      r.x = acc[i][c][0] + bp.x + cx.x;
      r.y = acc[i][c][1] + bp.y + cx.y;
      r.z = acc[i][c][2] + bp.z + cx.z;
      r.w = acc[i][c][3] + bp.w + cx.w;
      *(float4*)&xf[(size_t)srow * DD + fb] = r;
    }
  }
}

// ==== attention: S^T = K·Q^T; P stays in registers (k-permuted PV) ====
// block = 128 q-rows x one (b,h); 4 waves x 32 q-rows; 64-key tiles.
// Double-buffered GLLDS staging (pre-swizzled global src, linear LDS dest,
// XOR-swizzled read side); softmax p = exp2(fma(sc,ka,kb)) with precomputed
// per-key coeffs; row-sum via ones-MFMA; setprio(1) around compute.
__global__ __launch_bounds__(256) void attn_k(const unsigned short* __restrict__ Q,
                                              const unsigned short* __restrict__ K,
                                              const unsigned short* __restrict__ Vt,
                                              const float* __restrict__ ka,
                                              const float* __restrict__ kb,
                                              unsigned short* __restrict__ O) {
  __shared__ unsigned short Ks[2 * 64 * 64];   // 2 x 8KB, [key][dd] 16B-chunk XOR-swizzled
  __shared__ unsigned short Vts[2 * 64 * 64];  // 2 x 8KB, [hd][key] same swizzle
  const int tid = threadIdx.x;
  const int w = tid >> 6, lane = tid & 63;
  const int quad = lane >> 4, l16 = lane & 15;
  const int bh = blockIdx.y;
  const int b = bh / HH, h = bh - b * HH;
  const int q0 = blockIdx.x << 7;
  const unsigned short* Qb = Q + (size_t)bh * (SS * HDD);
  const unsigned short* Kb = K + (size_t)bh * (SS * HDD);
  const unsigned short* Vtb = Vt + (size_t)bh * (SS * HDD);
  const float* ka_b = ka + b * SS;
  const float* kb_b = kb + b * SS;

  // Q fragments (B-operand: n=q=l16, k=dd natural)
  bf16x8 qf[2][2];
#pragma unroll
  for (int qi = 0; qi < 2; ++qi)
#pragma unroll
    for (int f = 0; f < 2; ++f)
      qf[qi][f] = *(const bf16x8*)&Qb[(size_t)(q0 + w * 32 + qi * 16 + l16) * HDD + f * 32 + quad * 8];

  fx4 o[2][4];
#pragma unroll
  for (int qi = 0; qi < 2; ++qi)
#pragma unroll
    for (int ht = 0; ht < 4; ++ht) o[qi][ht] = (fx4){0.f, 0.f, 0.f, 0.f};
  fx4 sacc[2];
  sacc[0] = (fx4){0.f, 0.f, 0.f, 0.f};
  sacc[1] = (fx4){0.f, 0.f, 0.f, 0.f};

  // ones fragment for row-sum MFMA (A all 1.0bf16 -> D[m][q] = sum_k P[k][q])
  const ix4 one4 = (ix4){0x3F803F80, 0x3F803F80, 0x3F803F80, 0x3F803F80};
  const bf16x8 onesf = __builtin_bit_cast(bf16x8, one4);

  // staging: 512 chunks of 16B per matrix; chunk c -> LDS byte c*16 (linear);
  // global source pre-swizzled: row r = c>>3, slot p = (c&7)^(r&7)
  const int cA = tid, cB = 256 + tid;
  const int rA = cA >> 3, pA = (cA & 7) ^ (rA & 7);
  const int rB = cB >> 3, pB = (cB & 7) ^ (rB & 7);
  const unsigned short* kSrcA = Kb + (size_t)rA * HDD + pA * 8;
  const unsigned short* kSrcB = Kb + (size_t)rB * HDD + pB * 8;
  const unsigned short* vSrcA = Vtb + (size_t)rA * SS + pA * 8;
  const unsigned short* vSrcB = Vtb + (size_t)rB * SS + pB * 8;
  const int wbA = w * 1024;          // wave's chunk-range A byte base within a buffer
  const int wbB = 4096 + w * 1024;   // chunk-range B

  // prologue: tile 0 -> buf 0
  GLLDS(kSrcA, (char*)Ks + wbA);
  GLLDS(kSrcB, (char*)Ks + wbB);
  GLLDS(vSrcA, (char*)Vts + wbA);
  GLLDS(vSrcB, (char*)Vts + wbB);
  int cur = 0;

  for (int k0 = 0; k0 < SS; k0 += 64) {
    __syncthreads();   // drains vmcnt -> buf[cur] ready; prev reads of buf[cur^1] done
    if (k0 + 64 < SS) {
      int kn = k0 + 64;
      GLLDS(kSrcA + (size_t)kn * HDD, (char*)Ks + (cur ^ 1) * 8192 + wbA);
      GLLDS(kSrcB + (size_t)kn * HDD, (char*)Ks + (cur ^ 1) * 8192 + wbB);
      GLLDS(vSrcA + kn, (char*)Vts + (cur ^ 1) * 8192 + wbA);
      GLLDS(vSrcB + kn, (char*)Vts + (cur ^ 1) * 8192 + wbB);
    }
    const unsigned short* Ksc = Ks + cur * 4096;
    const char* Vtsc = (const char*)Vts + cur * 8192;

    // precomputed mask coefficients (L2-hot, shared by all q-blocks of this b)
    float4 mqa[4], mqb[4];
#pragma unroll
    for (int kt = 0; kt < 4; ++kt) {
      mqa[kt] = *(const float4*)&ka_b[k0 + kt * 16 + quad * 4];
      mqb[kt] = *(const float4*)&kb_b[k0 + kt * 16 + quad * 4];
    }

    // K fragments (A-operand: m=key=l16, k=dd natural)
    bf16x8 kf[4][2];
#pragma unroll
    for (int kt = 0; kt < 4; ++kt) {
      int row = kt * 16 + l16;
      int rx = row & 7;
#pragma unroll
      for (int f = 0; f < 2; ++f)
        kf[kt][f] = *(const bf16x8*)&Ksc[row * 64 + ((f * 4 + quad) ^ rx) * 8];
    }
    // V fragments (A-operand: m=hd=l16, k-permuted: key=f*32+(j>>2)*16+quad*4+(j&3))
    bf16x8 vf[4][2];
#pragma unroll
    for (int ht = 0; ht < 4; ++ht) {
      int row = ht * 16 + l16;
      int rx = row & 7;
#pragma unroll
      for (int f = 0; f < 2; ++f) {
        int dc0 = (f * 4 + (quad >> 1)) ^ rx;
        int dc1 = (f * 4 + 2 + (quad >> 1)) ^ rx;
        uint2 lo = *(const uint2*)(Vtsc + row * 128 + dc0 * 16 + (quad & 1) * 8);
        uint2 hi = *(const uint2*)(Vtsc + row * 128 + dc1 * 16 + (quad & 1) * 8);
        ix4 vv = (ix4){(int)lo.x, (int)lo.y, (int)hi.x, (int)hi.y};
        vf[ht][f] = __builtin_bit_cast(bf16x8, vv);
      }
    }

    __builtin_amdgcn_s_setprio(1);
#pragma unroll
    for (int qi = 0; qi < 2; ++qi) {
      unsigned pw[8];
#pragma unroll
      for (int kt = 0; kt < 4; ++kt) {
        fx4 s = (fx4){0.f, 0.f, 0.f, 0.f};
        s = MFMA16(kf[kt][0], qf[qi][0], s);
        s = MFMA16(kf[kt][1], qf[qi][1], s);
        const float* ma = (const float*)&mqa[kt];
        const float* mc = (const float*)&mqb[kt];
        float p0 = ex2(__builtin_fmaf(s[0], ma[0], mc[0]));
        float p1 = ex2(__builtin_fmaf(s[1], ma[1], mc[1]));
        float p2 = ex2(__builtin_fmaf(s[2], ma[2], mc[2]));
        float p3 = ex2(__builtin_fmaf(s[3], ma[3], mc[3]));
        pw[kt * 2]     = cvtpk(p0, p1);
        pw[kt * 2 + 1] = cvtpk(p2, p3);
      }
      ix4 pi0 = (ix4){(int)pw[0], (int)pw[1], (int)pw[2], (int)pw[3]};
      ix4 pi1 = (ix4){(int)pw[4], (int)pw[5], (int)pw[6], (int)pw[7]};
      bf16x8 pf0 = __builtin_bit_cast(bf16x8, pi0);
      bf16x8 pf1 = __builtin_bit_cast(bf16x8, pi1);
      // row-sum on the MFMA pipe
      sacc[qi] = MFMA16(onesf, pf0, sacc[qi]);
      sacc[qi] = MFMA16(onesf, pf1, sacc[qi]);
#pragma unroll
      for (int ht = 0; ht < 4; ++ht) {
        o[qi][ht] = MFMA16(vf[ht][0], pf0, o[qi][ht]);
        o[qi][ht] = MFMA16(vf[ht][1], pf1, o[qi][ht]);
      }
    }
    __builtin_amdgcn_s_setprio(0);
    cur ^= 1;
  }

#pragma unroll
  for (int qi = 0; qi < 2; ++qi) {
    // sacc rows are all identical (ones operand): lane's col l16 sum is in any reg
    float inv = 1.f / fmaxf(sacc[qi][0], 1e-30f);
    int sq = q0 + w * 32 + qi * 16 + l16;
    unsigned short* orow = O + ((size_t)(b * SS + sq)) * DD + h * HDD;
#pragma unroll
    for (int ht = 0; ht < 4; ++ht) {
      uint2 v = make_uint2(pkbf(o[qi][ht][0] * inv, o[qi][ht][1] * inv),
                           pkbf(o[qi][ht][2] * inv, o[qi][ht][3] * inv));
      *(uint2*)&orow[ht * 16 + quad * 4] = v;
    }
  }
}

// ---- LayerNorm over D=768: one block per row ----
__global__ __launch_bounds__(256) void ln_k(const float* __restrict__ x,
                                            const float* __restrict__ gamma,
                                            const float* __restrict__ beta,
                                            float* __restrict__ out) {
  const int row = blockIdx.x;
  const float* xr = x + (size_t)row * DD;
  const int t = threadIdx.x;
  float v0 = xr[t], v1 = xr[t + 256], v2 = xr[t + 512];
  float s = v0 + v1 + v2;
  float ss = v0 * v0 + v1 * v1 + v2 * v2;
#pragma unroll
  for (int d = 32; d > 0; d >>= 1) {
    s += __shfl_down(s, d);
    ss += __shfl_down(ss, d);
  }
  __shared__ float sh[10];
  int wv = t >> 6, lane = t & 63;
  if (lane == 0) { sh[wv] = s; sh[4 + wv] = ss; }
  __syncthreads();
  if (t == 0) {
    float S = sh[0] + sh[1] + sh[2] + sh[3];
    float SSm = sh[4] + sh[5] + sh[6] + sh[7];
    float mu = S * (1.0f / DD);
    float var = SSm * (1.0f / DD) - mu * mu;
    sh[8] = mu;
    sh[9] = rsqrtf(var + 1e-5f);
  }
  __syncthreads();
  float mu = sh[8], rstd = sh[9];
  out[(size_t)row * DD + t]       = (v0 - mu) * rstd * gamma[t]       + beta[t];
  out[(size_t)row * DD + t + 256] = (v1 - mu) * rstd * gamma[t + 256] + beta[t + 256];
  out[(size_t)row * DD + t + 512] = (v2 - mu) * rstd * gamma[t + 512] + beta[t + 512];
}

extern "C" void kernel_launch(void* const* d_in, const int* in_sizes, int n_in,
                              void* d_out, int out_size, void* d_ws, size_t ws_size,
                              hipStream_t stream) {
  (void)in_sizes; (void)n_in; (void)out_size; (void)ws_size;
  const float* ctx   = (const float*)d_in[0];
  const float* mask  = (const float*)d_in[1];
  const float* wqkv  = (const float*)d_in[2];
  const float* wproj = (const float*)d_in[3];
  const float* bproj = (const float*)d_in[4];
  const float* gamma = (const float*)d_in[5];
  const float* beta  = (const float*)d_in[6];
  float* out = (float*)d_out;

  char* p = (char*)d_ws;
  unsigned short* Xbf = (unsigned short*)p; p += (size_t)NEL * 2;
  unsigned short* Qw  = (unsigned short*)p; p += (size_t)NEL * 2;
  unsigned short* Kw  = (unsigned short*)p; p += (size_t)NEL * 2;
  unsigned short* Vtw = (unsigned short*)p; p += (size_t)NEL * 2;
  unsigned short* Ao  = (unsigned short*)p; p += (size_t)NEL * 2;
  unsigned short* WqkvT  = (unsigned short*)p; p += (size_t)DD * NQKV * 2;
  unsigned short* WprojT = (unsigned short*)p; p += (size_t)DD * DD * 2;
  float* kaw = (float*)p; p += (size_t)BS * 4;
  float* kbw = (float*)p; p += (size_t)BS * 4;
  float* xf = (float*)Qw;  // reuse Q+K region (attn done before proj writes)

  pack_bf16<<<NEL / 4 / 256, 256, 0, stream>>>(ctx, Xbf, NEL / 4);
  mask_coef_k<<<BS / 256, 256, 0, stream>>>(mask, kaw, kbw, BS);
  pack_transpose<<<dim3(NQKV / 32, DD / 32), 256, 0, stream>>>(wqkv, WqkvT, DD, NQKV);
  pack_transpose<<<dim3(DD / 32, DD / 32), 256, 0, stream>>>(wproj, WprojT, DD, DD);
  gemm_qkv_k<<<dim3(BS / 128, NQKV / 128), 256, 0, stream>>>(WqkvT, Xbf, Qw, Kw, Vtw);
  attn_k<<<dim3(SS / 128, BB * HH), 256, 0, stream>>>(Qw, Kw, Vtw, kaw, kbw, Ao);
  gemm_proj_k<<<dim3(BS / 128, DD / 128), 256, 0, stream>>>(WprojT, Ao, ctx, bproj, xf);
  ln_k<<<BS, 256, 0, stream>>>(xf, gamma, beta, out);
}

// Round 5
// 252.274 us; speedup vs baseline: 1.1009x; 1.1009x over previous
//
#include <hip/hip_runtime.h>

// ---- constants for B=4, S=2048, D=768, H=12, HD=64 ----
#define BB 4
#define SS 2048
#define DD 768
#define HH 12
#define HDD 64
#define BS (BB*SS)            // 8192 rows
#define NQKV (3*DD)           // 2304
#define NEL (BS*DD)           // 6291456

typedef __attribute__((ext_vector_type(8))) __bf16 bf16x8;
typedef __attribute__((ext_vector_type(4))) float fx4;
typedef __attribute__((ext_vector_type(4))) int   ix4;

#define MFMA16(a,b,c) __builtin_amdgcn_mfma_f32_16x16x32_bf16((a),(b),(c),0,0,0)

// async global->LDS, 16B per lane, lane-linear dest (wave-uniform base + lane*16)
#define GLLDS(g, l) __builtin_amdgcn_global_load_lds( \
    (const __attribute__((address_space(1))) void*)(g), \
    (__attribute__((address_space(3))) void*)(l), 16, 0, 0)

__device__ __forceinline__ unsigned short f2bf(float f) {
  unsigned u = __builtin_bit_cast(unsigned, f);
  u = (u + 0x7FFFu + ((u >> 16) & 1u)) >> 16;
  return (unsigned short)u;
}
// pack two fp32 -> bf16 pair
__device__ __forceinline__ unsigned pkbf(float a, float b) {
  unsigned ua = __builtin_bit_cast(unsigned, a);
  unsigned ub = __builtin_bit_cast(unsigned, b);
  return ((ua + 0x8000u) >> 16) | ((ub + 0x8000u) & 0xFFFF0000u);
}
// hardware packed fp32->bf16 (RNE), 1 instr for 2 elems
__device__ __forceinline__ unsigned cvtpk(float a, float b) {
  unsigned r;
  asm("v_cvt_pk_bf16_f32 %0, %1, %2" : "=v"(r) : "v"(a), "v"(b));
  return r;
}
__device__ __forceinline__ float ex2(float x) { return __builtin_amdgcn_exp2f(x); }

// ---- pack fp32 -> bf16 (vectorized, 4 elems/thread) ----
__global__ __launch_bounds__(256) void pack_bf16(const float* __restrict__ x,
                                                 unsigned short* __restrict__ y, int n4) {
  int i = blockIdx.x * 256 + threadIdx.x;
  if (i < n4) {
    float4 v = ((const float4*)x)[i];
    ((uint2*)y)[i] = make_uint2(pkbf(v.x, v.y), pkbf(v.z, v.w));
  }
}

// ---- mask -> softmax coefficients: p = exp2(sc*ka + kb) ----
//   ka = m * 0.125*log2(e);  kb = (m-1)*1e10*log2(e)
__global__ __launch_bounds__(256) void mask_coef_k(const float* __restrict__ m,
                                                   float* __restrict__ ka,
                                                   float* __restrict__ kb, int n) {
  int i = blockIdx.x * 256 + threadIdx.x;
  if (i < n) {
    float v = m[i];
    ka[i] = v * 0.18033688f;
    kb[i] = __builtin_fmaf(v, 1.44269504e10f, -1.44269504e10f);
  }
}

// ---- tiled pack+transpose: w (K x N) fp32 -> wT (N x K) bf16 ----
__global__ __launch_bounds__(256) void pack_transpose(const float* __restrict__ w,
                                                      unsigned short* __restrict__ wT,
                                                      int K, int N) {
  __shared__ unsigned short t[32][33];
  int n0 = blockIdx.x * 32, k0 = blockIdx.y * 32;
  int tx = threadIdx.x & 31, ty = threadIdx.x >> 5;
#pragma unroll
  for (int r = ty; r < 32; r += 8)
    t[tx][r] = f2bf(w[(size_t)(k0 + r) * N + n0 + tx]);
  __syncthreads();
#pragma unroll
  for (int r = ty; r < 32; r += 8)
    wT[(size_t)(n0 + r) * K + k0 + tx] = t[r][tx];
}

// ==== QKV GEMM: C^T[feature][seq] = Wt(2304x768) x X(8192x768)^T ====
// 128x128 tile, BK=32, double-buffered GLLDS (1 barrier/tile, prefetch in flight
// under compute; no global loads inside compute phase), 4 waves x 64x64.
__global__ __launch_bounds__(256) void gemm_qkv_k(const unsigned short* __restrict__ Wt,
                                                  const unsigned short* __restrict__ X,
                                                  unsigned short* __restrict__ Qo,
                                                  unsigned short* __restrict__ Ko,
                                                  unsigned short* __restrict__ Vto) {
  __shared__ unsigned short As[2 * 128 * 32];   // 2 x 8KB
  __shared__ unsigned short Bs[2 * 128 * 32];
  const int tid = threadIdx.x;
  const int w = tid >> 6, lane = tid & 63, quad = lane >> 4, l16 = lane & 15;
  const int m0 = blockIdx.y << 7;   // feature
  const int n0 = blockIdx.x << 7;   // seq row
  const int wm = (w & 1) * 64, wn = (w >> 1) * 64;
  fx4 acc[4][4];
#pragma unroll
  for (int i = 0; i < 4; ++i)
#pragma unroll
    for (int c = 0; c < 4; ++c) acc[i][c] = (fx4){0.f, 0.f, 0.f, 0.f};

  const int c0 = tid, c1 = 256 + tid;
  const unsigned short* Ag0 = Wt + (size_t)(m0 + (c0 >> 2)) * DD + (c0 & 3) * 8;
  const unsigned short* Ag1 = Wt + (size_t)(m0 + (c1 >> 2)) * DD + (c1 & 3) * 8;
  const unsigned short* Bg0 = X + (size_t)(n0 + (c0 >> 2)) * DD + (c0 & 3) * 8;
  const unsigned short* Bg1 = X + (size_t)(n0 + (c1 >> 2)) * DD + (c1 & 3) * 8;
  const int wb = w * 1024;   // wave's lane-linear LDS byte base

  // prologue: tile 0 -> buf 0
  GLLDS(Ag0, (char*)As + wb);
  GLLDS(Ag1, (char*)As + 4096 + wb);
  GLLDS(Bg0, (char*)Bs + wb);
  GLLDS(Bg1, (char*)Bs + 4096 + wb);
  int cur = 0;

  for (int k0 = 0; k0 < DD; k0 += 32) {
    __syncthreads();   // drains vmcnt -> buf[cur] ready; prev reads of buf[cur^1] done
    if (k0 + 32 < DD) {
      GLLDS(Ag0 + k0 + 32, (char*)As + (cur ^ 1) * 8192 + wb);
      GLLDS(Ag1 + k0 + 32, (char*)As + (cur ^ 1) * 8192 + 4096 + wb);
      GLLDS(Bg0 + k0 + 32, (char*)Bs + (cur ^ 1) * 8192 + wb);
      GLLDS(Bg1 + k0 + 32, (char*)Bs + (cur ^ 1) * 8192 + 4096 + wb);
    }
    const unsigned short* Asc = As + cur * 4096;
    const unsigned short* Bsc = Bs + cur * 4096;
    bf16x8 af[4], bf[4];
#pragma unroll
    for (int i = 0; i < 4; ++i) af[i] = *(const bf16x8*)&Asc[(wm + i * 16 + l16) * 32 + quad * 8];
#pragma unroll
    for (int c = 0; c < 4; ++c) bf[c] = *(const bf16x8*)&Bsc[(wn + c * 16 + l16) * 32 + quad * 8];
#pragma unroll
    for (int i = 0; i < 4; ++i)
#pragma unroll
      for (int c = 0; c < 4; ++c) acc[i][c] = MFMA16(af[i], bf[c], acc[i][c]);
    cur ^= 1;
  }

  const int which = m0 / DD;  // block-uniform: 0=Q 1=K 2=V (768 = 6*128, no straddle)
#pragma unroll
  for (int i = 0; i < 4; ++i) {
    int fb = m0 + wm + i * 16 + quad * 4;
    int d = fb - which * DD;
    int h = d >> 6, hd = d & 63;
#pragma unroll
    for (int c = 0; c < 4; ++c) {
      int srow = n0 + wn + c * 16 + l16;
      int b = srow >> 11, s = srow & (SS - 1);
      if (which == 0) {
        uint2 v = make_uint2(pkbf(acc[i][c][0], acc[i][c][1]), pkbf(acc[i][c][2], acc[i][c][3]));
        *(uint2*)&Qo[((size_t)(b * HH + h) * SS + s) * HDD + hd] = v;
      } else if (which == 1) {
        uint2 v = make_uint2(pkbf(acc[i][c][0], acc[i][c][1]), pkbf(acc[i][c][2], acc[i][c][3]));
        *(uint2*)&Ko[((size_t)(b * HH + h) * SS + s) * HDD + hd] = v;
      } else {
#pragma unroll
        for (int r = 0; r < 4; ++r)
          Vto[((size_t)(b * HH + h) * HDD + hd + r) * SS + s] = f2bf(acc[i][c][r]);
      }
    }
  }
}

// ==== proj GEMM: C^T[feat][seq] = WprojT(768x768) x Ao(8192x768)^T ====
// epilogue: + b_proj + residual(ctx), fp32 out (feeds LN)
__global__ __launch_bounds__(256) void gemm_proj_k(const unsigned short* __restrict__ Wt,
                                                   const unsigned short* __restrict__ X,
                                                   const float* __restrict__ ctx,
                                                   const float* __restrict__ bproj,
                                                   float* __restrict__ xf) {
  __shared__ unsigned short As[2 * 128 * 32];
  __shared__ unsigned short Bs[2 * 128 * 32];
  const int tid = threadIdx.x;
  const int w = tid >> 6, lane = tid & 63, quad = lane >> 4, l16 = lane & 15;
  const int m0 = blockIdx.y << 7;
  const int n0 = blockIdx.x << 7;
  const int wm = (w & 1) * 64, wn = (w >> 1) * 64;
  fx4 acc[4][4];
#pragma unroll
  for (int i = 0; i < 4; ++i)
#pragma unroll
    for (int c = 0; c < 4; ++c) acc[i][c] = (fx4){0.f, 0.f, 0.f, 0.f};

  const int c0 = tid, c1 = 256 + tid;
  const unsigned short* Ag0 = Wt + (size_t)(m0 + (c0 >> 2)) * DD + (c0 & 3) * 8;
  const unsigned short* Ag1 = Wt + (size_t)(m0 + (c1 >> 2)) * DD + (c1 & 3) * 8;
  const unsigned short* Bg0 = X + (size_t)(n0 + (c0 >> 2)) * DD + (c0 & 3) * 8;
  const unsigned short* Bg1 = X + (size_t)(n0 + (c1 >> 2)) * DD + (c1 & 3) * 8;
  const int wb = w * 1024;

  GLLDS(Ag0, (char*)As + wb);
  GLLDS(Ag1, (char*)As + 4096 + wb);
  GLLDS(Bg0, (char*)Bs + wb);
  GLLDS(Bg1, (char*)Bs + 4096 + wb);
  int cur = 0;

  for (int k0 = 0; k0 < DD; k0 += 32) {
    __syncthreads();
    if (k0 + 32 < DD) {
      GLLDS(Ag0 + k0 + 32, (char*)As + (cur ^ 1) * 8192 + wb);
      GLLDS(Ag1 + k0 + 32, (char*)As + (cur ^ 1) * 8192 + 4096 + wb);
      GLLDS(Bg0 + k0 + 32, (char*)Bs + (cur ^ 1) * 8192 + wb);
      GLLDS(Bg1 + k0 + 32, (char*)Bs + (cur ^ 1) * 8192 + 4096 + wb);
    }
    const unsigned short* Asc = As + cur * 4096;
    const unsigned short* Bsc = Bs + cur * 4096;
    bf16x8 af[4], bf[4];
#pragma unroll
    for (int i = 0; i < 4; ++i) af[i] = *(const bf16x8*)&Asc[(wm + i * 16 + l16) * 32 + quad * 8];
#pragma unroll
    for (int c = 0; c < 4; ++c) bf[c] = *(const bf16x8*)&Bsc[(wn + c * 16 + l16) * 32 + quad * 8];
#pragma unroll
    for (int i = 0; i < 4; ++i)
#pragma unroll
      for (int c = 0; c < 4; ++c) acc[i][c] = MFMA16(af[i], bf[c], acc[i][c]);
    cur ^= 1;
  }

#pragma unroll
  for (int i = 0; i < 4; ++i) {
    int fb = m0 + wm + i * 16 + quad * 4;
    float4 bp = *(const float4*)&bproj[fb];
#pragma unroll
    for (int c = 0; c < 4; ++c) {
      int srow = n0 + wn + c * 16 + l16;
      float4 cx = *(const float4*)&ctx[(size_t)srow * DD + fb];
      float4 r;
      r.x = acc[i][c][0] + bp.x + cx.x;
      r.y = acc[i][c][1] + bp.y + cx.y;
      r.z = acc[i][c][2] + bp.z + cx.z;
      r.w = acc[i][c][3] + bp.w + cx.w;
      *(float4*)&xf[(size_t)srow * DD + fb] = r;
    }
  }
}

// ==== attention: S^T = K·Q^T; P stays in registers (k-permuted PV) ====
// block = 128 q-rows x one (b,h); 4 waves x 32 q-rows; 64-key tiles.
// Round-2 staging structure (reg prefetch + ds_write, 2 barriers) — loads land
// during compute, drain at next ds_write. Mask coeffs staged in LDS once so the
// compute phase has ZERO vmcnt-coupled loads (the round-3 serializer).
__global__ __launch_bounds__(256) void attn_k(const unsigned short* __restrict__ Q,
                                              const unsigned short* __restrict__ K,
                                              const unsigned short* __restrict__ Vt,
                                              const float* __restrict__ ka,
                                              const float* __restrict__ kb,
                                              unsigned short* __restrict__ O) {
  __shared__ unsigned short Ks[64 * 64];   // [key][dd], 16B chunks XOR-swizzled by row&7
  __shared__ unsigned short Vts[64 * 64];  // [hd][key], same swizzle
  __shared__ float kaS[SS];                // per-key softmax coeff a (8KB)
  __shared__ float kbS[SS];                // per-key softmax coeff b (8KB)
  const int tid = threadIdx.x;
  const int w = tid >> 6, lane = tid & 63;
  const int quad = lane >> 4, l16 = lane & 15;
  const int bh = blockIdx.y;
  const int b = bh / HH, h = bh - b * HH;
  const int q0 = blockIdx.x << 7;
  const unsigned short* Qb = Q + (size_t)bh * (SS * HDD);
  const unsigned short* Kb = K + (size_t)bh * (SS * HDD);
  const unsigned short* Vtb = Vt + (size_t)bh * (SS * HDD);
  const float* ka_b = ka + b * SS;
  const float* kb_b = kb + b * SS;

  // one-time: stage coefficient tables to LDS (visible after first loop barriers)
#pragma unroll
  for (int i = 0; i < 2; ++i) {
    int idx = i * 256 + tid;                        // 512 float4 per table
    ((float4*)kaS)[idx] = ((const float4*)ka_b)[idx];
    ((float4*)kbS)[idx] = ((const float4*)kb_b)[idx];
  }

  // Q fragments (B-operand: n=q=l16, k=dd natural)
  bf16x8 qf[2][2];
#pragma unroll
  for (int qi = 0; qi < 2; ++qi)
#pragma unroll
    for (int f = 0; f < 2; ++f)
      qf[qi][f] = *(const bf16x8*)&Qb[(size_t)(q0 + w * 32 + qi * 16 + l16) * HDD + f * 32 + quad * 8];

  fx4 o[2][4];
#pragma unroll
  for (int qi = 0; qi < 2; ++qi)
#pragma unroll
    for (int ht = 0; ht < 4; ++ht) o[qi][ht] = (fx4){0.f, 0.f, 0.f, 0.f};
  fx4 sacc[2];
  sacc[0] = (fx4){0.f, 0.f, 0.f, 0.f};
  sacc[1] = (fx4){0.f, 0.f, 0.f, 0.f};

  // ones fragment for row-sum MFMA (A all 1.0bf16 -> D[m][q] = sum_k P[k][q])
  const ix4 one4 = (ix4){0x3F803F80, 0x3F803F80, 0x3F803F80, 0x3F803F80};
  const bf16x8 onesf = __builtin_bit_cast(bf16x8, one4);

  // staging: 512 chunks of 16B per matrix; 2 per thread; XOR-swizzled placement
  const int cA = tid, cB = 256 + tid;
  const int rA = cA >> 3, pA = (cA & 7) ^ (rA & 7);
  const int rB = cB >> 3, pB = (cB & 7) ^ (rB & 7);

  ix4 rk0 = *(const ix4*)&Kb[(size_t)rA * HDD + pA * 8];
  ix4 rk1 = *(const ix4*)&Kb[(size_t)rB * HDD + pB * 8];
  ix4 rv0 = *(const ix4*)&Vtb[(size_t)rA * SS + pA * 8];
  ix4 rv1 = *(const ix4*)&Vtb[(size_t)rB * SS + pB * 8];

  for (int k0 = 0; k0 < SS; k0 += 64) {
    __syncthreads();
    *(ix4*)((char*)Ks + cA * 16) = rk0;
    *(ix4*)((char*)Ks + cB * 16) = rk1;
    *(ix4*)((char*)Vts + cA * 16) = rv0;
    *(ix4*)((char*)Vts + cB * 16) = rv1;
    __syncthreads();
    if (k0 + 64 < SS) {
      int kn = k0 + 64;
      rk0 = *(const ix4*)&Kb[(size_t)(kn + rA) * HDD + pA * 8];
      rk1 = *(const ix4*)&Kb[(size_t)(kn + rB) * HDD + pB * 8];
      rv0 = *(const ix4*)&Vtb[(size_t)rA * SS + kn + pA * 8];
      rv1 = *(const ix4*)&Vtb[(size_t)rB * SS + kn + pB * 8];
    }

    // mask coefficients from LDS (lgkmcnt only — no vmcnt coupling with prefetch)
    float4 mqa[4], mqb[4];
#pragma unroll
    for (int kt = 0; kt < 4; ++kt) {
      mqa[kt] = *(const float4*)&kaS[k0 + kt * 16 + quad * 4];
      mqb[kt] = *(const float4*)&kbS[k0 + kt * 16 + quad * 4];
    }

    // K fragments (A-operand: m=key=l16, k=dd natural)
    bf16x8 kf[4][2];
#pragma unroll
    for (int kt = 0; kt < 4; ++kt) {
      int row = kt * 16 + l16;
      int rx = row & 7;
#pragma unroll
      for (int f = 0; f < 2; ++f)
        kf[kt][f] = *(const bf16x8*)&Ks[row * 64 + ((f * 4 + quad) ^ rx) * 8];
    }
    // V fragments (A-operand: m=hd=l16, k-permuted: key=f*32+(j>>2)*16+quad*4+(j&3))
    bf16x8 vf[4][2];
#pragma unroll
    for (int ht = 0; ht < 4; ++ht) {
      int row = ht * 16 + l16;
      int rx = row & 7;
#pragma unroll
      for (int f = 0; f < 2; ++f) {
        int dc0 = (f * 4 + (quad >> 1)) ^ rx;
        int dc1 = (f * 4 + 2 + (quad >> 1)) ^ rx;
        uint2 lo = *(const uint2*)((const char*)Vts + row * 128 + dc0 * 16 + (quad & 1) * 8);
        uint2 hi = *(const uint2*)((const char*)Vts + row * 128 + dc1 * 16 + (quad & 1) * 8);
        ix4 vv = (ix4){(int)lo.x, (int)lo.y, (int)hi.x, (int)hi.y};
        vf[ht][f] = __builtin_bit_cast(bf16x8, vv);
      }
    }

#pragma unroll
    for (int qi = 0; qi < 2; ++qi) {
      unsigned pw[8];
#pragma unroll
      for (int kt = 0; kt < 4; ++kt) {
        fx4 s = (fx4){0.f, 0.f, 0.f, 0.f};
        s = MFMA16(kf[kt][0], qf[qi][0], s);
        s = MFMA16(kf[kt][1], qf[qi][1], s);
        const float* ma = (const float*)&mqa[kt];
        const float* mc = (const float*)&mqb[kt];
        float p0 = ex2(__builtin_fmaf(s[0], ma[0], mc[0]));
        float p1 = ex2(__builtin_fmaf(s[1], ma[1], mc[1]));
        float p2 = ex2(__builtin_fmaf(s[2], ma[2], mc[2]));
        float p3 = ex2(__builtin_fmaf(s[3], ma[3], mc[3]));
        pw[kt * 2]     = cvtpk(p0, p1);
        pw[kt * 2 + 1] = cvtpk(p2, p3);
      }
      ix4 pi0 = (ix4){(int)pw[0], (int)pw[1], (int)pw[2], (int)pw[3]};
      ix4 pi1 = (ix4){(int)pw[4], (int)pw[5], (int)pw[6], (int)pw[7]};
      bf16x8 pf0 = __builtin_bit_cast(bf16x8, pi0);
      bf16x8 pf1 = __builtin_bit_cast(bf16x8, pi1);
      // row-sum on the MFMA pipe
      sacc[qi] = MFMA16(onesf, pf0, sacc[qi]);
      sacc[qi] = MFMA16(onesf, pf1, sacc[qi]);
#pragma unroll
      for (int ht = 0; ht < 4; ++ht) {
        o[qi][ht] = MFMA16(vf[ht][0], pf0, o[qi][ht]);
        o[qi][ht] = MFMA16(vf[ht][1], pf1, o[qi][ht]);
      }
    }
  }

#pragma unroll
  for (int qi = 0; qi < 2; ++qi) {
    // sacc rows are all identical (ones operand): lane's col l16 sum is in any reg
    float inv = 1.f / fmaxf(sacc[qi][0], 1e-30f);
    int sq = q0 + w * 32 + qi * 16 + l16;
    unsigned short* orow = O + ((size_t)(b * SS + sq)) * DD + h * HDD;
#pragma unroll
    for (int ht = 0; ht < 4; ++ht) {
      uint2 v = make_uint2(pkbf(o[qi][ht][0] * inv, o[qi][ht][1] * inv),
                           pkbf(o[qi][ht][2] * inv, o[qi][ht][3] * inv));
      *(uint2*)&orow[ht * 16 + quad * 4] = v;
    }
  }
}

// ---- LayerNorm over D=768: one block per row ----
__global__ __launch_bounds__(256) void ln_k(const float* __restrict__ x,
                                            const float* __restrict__ gamma,
                                            const float* __restrict__ beta,
                                            float* __restrict__ out) {
  const int row = blockIdx.x;
  const float* xr = x + (size_t)row * DD;
  const int t = threadIdx.x;
  float v0 = xr[t], v1 = xr[t + 256], v2 = xr[t + 512];
  float s = v0 + v1 + v2;
  float ss = v0 * v0 + v1 * v1 + v2 * v2;
#pragma unroll
  for (int d = 32; d > 0; d >>= 1) {
    s += __shfl_down(s, d);
    ss += __shfl_down(ss, d);
  }
  __shared__ float sh[10];
  int wv = t >> 6, lane = t & 63;
  if (lane == 0) { sh[wv] = s; sh[4 + wv] = ss; }
  __syncthreads();
  if (t == 0) {
    float S = sh[0] + sh[1] + sh[2] + sh[3];
    float SSm = sh[4] + sh[5] + sh[6] + sh[7];
    float mu = S * (1.0f / DD);
    float var = SSm * (1.0f / DD) - mu * mu;
    sh[8] = mu;
    sh[9] = rsqrtf(var + 1e-5f);
  }
  __syncthreads();
  float mu = sh[8], rstd = sh[9];
  out[(size_t)row * DD + t]       = (v0 - mu) * rstd * gamma[t]       + beta[t];
  out[(size_t)row * DD + t + 256] = (v1 - mu) * rstd * gamma[t + 256] + beta[t + 256];
  out[(size_t)row * DD + t + 512] = (v2 - mu) * rstd * gamma[t + 512] + beta[t + 512];
}

extern "C" void kernel_launch(void* const* d_in, const int* in_sizes, int n_in,
                              void* d_out, int out_size, void* d_ws, size_t ws_size,
                              hipStream_t stream) {
  (void)in_sizes; (void)n_in; (void)out_size; (void)ws_size;
  const float* ctx   = (const float*)d_in[0];
  const float* mask  = (const float*)d_in[1];
  const float* wqkv  = (const float*)d_in[2];
  const float* wproj = (const float*)d_in[3];
  const float* bproj = (const float*)d_in[4];
  const float* gamma = (const float*)d_in[5];
  const float* beta  = (const float*)d_in[6];
  float* out = (float*)d_out;

  char* p = (char*)d_ws;
  unsigned short* Xbf = (unsigned short*)p; p += (size_t)NEL * 2;
  unsigned short* Qw  = (unsigned short*)p; p += (size_t)NEL * 2;
  unsigned short* Kw  = (unsigned short*)p; p += (size_t)NEL * 2;
  unsigned short* Vtw = (unsigned short*)p; p += (size_t)NEL * 2;
  unsigned short* Ao  = (unsigned short*)p; p += (size_t)NEL * 2;
  unsigned short* WqkvT  = (unsigned short*)p; p += (size_t)DD * NQKV * 2;
  unsigned short* WprojT = (unsigned short*)p; p += (size_t)DD * DD * 2;
  float* kaw = (float*)p; p += (size_t)BS * 4;
  float* kbw = (float*)p; p += (size_t)BS * 4;
  float* xf = (float*)Qw;  // reuse Q+K region (attn done before proj writes)

  pack_bf16<<<NEL / 4 / 256, 256, 0, stream>>>(ctx, Xbf, NEL / 4);
  mask_coef_k<<<BS / 256, 256, 0, stream>>>(mask, kaw, kbw, BS);
  pack_transpose<<<dim3(NQKV / 32, DD / 32), 256, 0, stream>>>(wqkv, WqkvT, DD, NQKV);
  pack_transpose<<<dim3(DD / 32, DD / 32), 256, 0, stream>>>(wproj, WprojT, DD, DD);
  gemm_qkv_k<<<dim3(BS / 128, NQKV / 128), 256, 0, stream>>>(WqkvT, Xbf, Qw, Kw, Vtw);
  attn_k<<<dim3(SS / 128, BB * HH), 256, 0, stream>>>(Qw, Kw, Vtw, kaw, kbw, Ao);
  gemm_proj_k<<<dim3(BS / 128, DD / 128), 256, 0, stream>>>(WprojT, Ao, ctx, bproj, xf);
  ln_k<<<BS, 256, 0, stream>>>(xf, gamma, beta, out);
}